// Round 3
// baseline (483.662 us; speedup 1.0000x reference)
//
#include <hip/hip_runtime.h>
#include <hip/hip_fp16.h>

// GCN layer: out = leaky_relu( segment_sum(edge_vals[:,None] * embeds[col], row, N), 0.5 )
// E = 3.2M, N = 100000, D = 128, f32 in/out.
//
// R5: reduce was latency-structure bound (two sequential waits per hop) and
//     build was atomic-MLP bound (one outstanding atomicExch per thread).
//     (a) 1-deep software pipeline in the chase: next node loads issue before
//         the gather wait -> one memory latency per iteration, not two.
//     (b) NCHAIN=8 parity chains (column-major heads, 400KB apart): serial
//         depth ~13.5 -> ~9.5 hops; build contention per word 8 -> 4.
//     (c) build processes 4 edges per round: 4 atomicExch in flight, one wait,
//         4 node stores. Build blocks dispatch before conversion blocks.
// Kept: packed 16B nodes, fp16 gather table (fused f32->f16 conversion),
//       non-temporal streaming hints, fused leaky_relu.

#define GCN_D       128
#define LEAKY_SLOPE 0.5f
#define NCHAIN      8
#define NCHAIN_FB   4

typedef int   i32x4 __attribute__((ext_vector_type(4)));
typedef float f32x2 __attribute__((ext_vector_type(2)));
typedef float f32x4 __attribute__((ext_vector_type(4)));
typedef unsigned int u32x4 __attribute__((ext_vector_type(4)));

__device__ inline unsigned pack_half2(float a, float b) {
    __half2 h = __floats2half2_rn(a, b);
    return *reinterpret_cast<unsigned*>(&h);
}

// ---------------- R5 fast path ----------------

// Blocks [0, buildBlocks) build the 8-parity chain structure (4-edge batches);
// blocks [buildBlocks, grid) convert embeds f32 -> f16 (streaming, nt).
__global__ void build_convert_kernel(const int* __restrict__ row,
                                     const int* __restrict__ col,
                                     const float* __restrict__ val,
                                     int E, int N,
                                     const f32x4* __restrict__ emb4,  // N*32
                                     int n8,                          // N*16
                                     u32x4* __restrict__ h8,          // N*16
                                     int* __restrict__ head,          // [NCHAIN][N]
                                     i32x4* __restrict__ node,
                                     int buildBlocks) {
    if ((int)blockIdx.x < buildBlocks) {
        int T = buildBlocks * blockDim.x;            // build threads
        int t = blockIdx.x * blockDim.x + threadIdx.x;
        for (int base = 0; base < E; base += 4 * T) {
            int i0 = base + t, i1 = i0 + T, i2 = i1 + T, i3 = i2 + T;
            bool a0 = i0 < E, a1 = i1 < E, a2 = i2 < E, a3 = i3 < E;

            int r0 = a0 ? row[i0] : 0;  int c0 = a0 ? col[i0] : 0;
            int r1 = a1 ? row[i1] : 0;  int c1 = a1 ? col[i1] : 0;
            int r2 = a2 ? row[i2] : 0;  int c2 = a2 ? col[i2] : 0;
            int r3 = a3 ? row[i3] : 0;  int c3 = a3 ? col[i3] : 0;
            float v0 = a0 ? val[i0] : 0.f;
            float v1 = a1 ? val[i1] : 0.f;
            float v2 = a2 ? val[i2] : 0.f;
            float v3 = a3 ? val[i3] : 0.f;

            // 4 far-atomics in flight per thread.
            int p0 = 0, p1 = 0, p2 = 0, p3 = 0;
            if (a0) p0 = atomicExch(&head[(i0 & (NCHAIN - 1)) * N + r0], i0);
            if (a1) p1 = atomicExch(&head[(i1 & (NCHAIN - 1)) * N + r1], i1);
            if (a2) p2 = atomicExch(&head[(i2 & (NCHAIN - 1)) * N + r2], i2);
            if (a3) p3 = atomicExch(&head[(i3 & (NCHAIN - 1)) * N + r3], i3);

            i32x4 nd;
            if (a0) { nd.x = p0; nd.y = c0; nd.z = __float_as_int(v0); nd.w = 0;
                      __builtin_nontemporal_store(nd, &node[i0]); }
            if (a1) { nd.x = p1; nd.y = c1; nd.z = __float_as_int(v1); nd.w = 0;
                      __builtin_nontemporal_store(nd, &node[i1]); }
            if (a2) { nd.x = p2; nd.y = c2; nd.z = __float_as_int(v2); nd.w = 0;
                      __builtin_nontemporal_store(nd, &node[i2]); }
            if (a3) { nd.x = p3; nd.y = c3; nd.z = __float_as_int(v3); nd.w = 0;
                      __builtin_nontemporal_store(nd, &node[i3]); }
        }
    } else {
        int bid = (int)blockIdx.x - buildBlocks;
        int nb  = (int)gridDim.x - buildBlocks;
        int stride = nb * blockDim.x;
        for (int i = bid * blockDim.x + threadIdx.x; i < n8; i += stride) {
            f32x4 a = __builtin_nontemporal_load(&emb4[2 * i]);
            f32x4 b = __builtin_nontemporal_load(&emb4[2 * i + 1]);
            u32x4 o;
            o.x = pack_half2(a.x, a.y);
            o.y = pack_half2(a.z, a.w);
            o.z = pack_half2(b.x, b.y);
            o.w = pack_half2(b.z, b.w);
            __builtin_nontemporal_store(o, &h8[i]);
        }
    }
}

// One wave per output row; lane owns 2 consecutive columns (half2 gather).
// Chases 8 chains branch-free with a 1-deep node-load pipeline.
__global__ void __launch_bounds__(256)
reduce_half8_kernel(const int* __restrict__ head,   // [NCHAIN][N]
                    const i32x4* __restrict__ node,
                    const __half2* __restrict__ ebh, // N*64 half2
                    float* __restrict__ out,
                    int N) {
    int wave = (int)((blockIdx.x * (long long)blockDim.x + threadIdx.x) >> 6);
    int lane = threadIdx.x & 63;
    if (wave >= N) return;

    int e[NCHAIN];
    #pragma unroll
    for (int k = 0; k < NCHAIN; ++k) e[k] = head[k * N + wave];

    // Prologue: node loads for the head edges (dead chains clamp to node[0]).
    i32x4 n[NCHAIN];
    #pragma unroll
    for (int k = 0; k < NCHAIN; ++k) {
        int idx = e[k] >= 0 ? e[k] : 0;
        n[k] = __builtin_nontemporal_load(&node[idx]);
    }

    float ax = 0.f, ay = 0.f;

    int alive = -1;
    #pragma unroll
    for (int k = 0; k < NCHAIN; ++k) alive &= e[k];

    while (alive != -1) {
        int   en[NCHAIN];
        int   c[NCHAIN];
        float v[NCHAIN];
        #pragma unroll
        for (int k = 0; k < NCHAIN; ++k) {
            bool a = e[k] >= 0;
            en[k] = a ? n[k].x : -1;
            c[k]  = a ? n[k].y : 0;
            v[k]  = a ? __int_as_float(n[k].z) : 0.f;
        }

        // Issue NEXT iteration's node loads before this iteration's gather
        // wait -> their latency hides under the gathers.
        i32x4 nn[NCHAIN];
        #pragma unroll
        for (int k = 0; k < NCHAIN; ++k) {
            int idx = en[k] >= 0 ? en[k] : 0;
            nn[k] = __builtin_nontemporal_load(&node[idx]);
        }

        // 8 independent coalesced 256 B fp16 gathers.
        __half2 m[NCHAIN];
        #pragma unroll
        for (int k = 0; k < NCHAIN; ++k)
            m[k] = ebh[(long long)c[k] * 64 + lane];

        #pragma unroll
        for (int k = 0; k < NCHAIN; ++k) {
            float2 f = __half22float2(m[k]);
            ax += v[k] * f.x;
            ay += v[k] * f.y;
        }

        alive = -1;
        #pragma unroll
        for (int k = 0; k < NCHAIN; ++k) {
            e[k] = en[k];
            n[k] = nn[k];
            alive &= e[k];
        }
    }

    ax = ax > 0.f ? ax : LEAKY_SLOPE * ax;
    ay = ay > 0.f ? ay : LEAKY_SLOPE * ay;
    f32x2 o; o.x = ax; o.y = ay;
    __builtin_nontemporal_store(
        o, reinterpret_cast<f32x2*>(out) + (long long)wave * 64 + lane);
}

// ---------------- R3 fallback: f32 gather, NCHAIN_FB=4 row-major ----------------

__global__ void build_nodes_kernel(const int* __restrict__ row,
                                   const int* __restrict__ col,
                                   const float* __restrict__ val,
                                   int E,
                                   int* __restrict__ head,
                                   int4* __restrict__ node) {
    int stride = gridDim.x * blockDim.x;
    for (int i = blockIdx.x * blockDim.x + threadIdx.x; i < E; i += stride) {
        int   r = row[i];
        int   c = col[i];
        float v = val[i];
        int prev = atomicExch(&head[r * NCHAIN_FB + (i & (NCHAIN_FB - 1))], i);
        node[i] = make_int4(prev, c, __float_as_int(v), 0);
    }
}

__global__ void __launch_bounds__(256)
reduce_nodes_kernel(const int* __restrict__ head,
                    const int4* __restrict__ node,
                    const float* __restrict__ embeds,
                    float* __restrict__ out,
                    int N) {
    int wave = (int)((blockIdx.x * (long long)blockDim.x + threadIdx.x) >> 6);
    int lane = threadIdx.x & 63;
    if (wave >= N) return;

    const float2* eb = reinterpret_cast<const float2*>(embeds);
    int4 h = reinterpret_cast<const int4*>(head)[wave];
    int e0 = h.x, e1 = h.y, e2 = h.z, e3 = h.w;

    float ax = 0.f, ay = 0.f;

    while ((e0 & e1 & e2 & e3) != -1) {
        int i0 = e0 >= 0 ? e0 : 0;
        int i1 = e1 >= 0 ? e1 : 0;
        int i2 = e2 >= 0 ? e2 : 0;
        int i3 = e3 >= 0 ? e3 : 0;

        int4 n0 = node[i0];
        int4 n1 = node[i1];
        int4 n2 = node[i2];
        int4 n3 = node[i3];

        int c0 = e0 >= 0 ? n0.y : 0;
        int c1 = e1 >= 0 ? n1.y : 0;
        int c2 = e2 >= 0 ? n2.y : 0;
        int c3 = e3 >= 0 ? n3.y : 0;

        float2 m0 = eb[(long long)c0 * 64 + lane];
        float2 m1 = eb[(long long)c1 * 64 + lane];
        float2 m2 = eb[(long long)c2 * 64 + lane];
        float2 m3 = eb[(long long)c3 * 64 + lane];

        float v0 = e0 >= 0 ? __int_as_float(n0.z) : 0.f;
        float v1 = e1 >= 0 ? __int_as_float(n1.z) : 0.f;
        float v2 = e2 >= 0 ? __int_as_float(n2.z) : 0.f;
        float v3 = e3 >= 0 ? __int_as_float(n3.z) : 0.f;

        ax += v0 * m0.x; ay += v0 * m0.y;
        ax += v1 * m1.x; ay += v1 * m1.y;
        ax += v2 * m2.x; ay += v2 * m2.y;
        ax += v3 * m3.x; ay += v3 * m3.y;

        e0 = e0 >= 0 ? n0.x : -1;
        e1 = e1 >= 0 ? n1.x : -1;
        e2 = e2 >= 0 ? n2.x : -1;
        e3 = e3 >= 0 ? n3.x : -1;
    }

    ax = ax > 0.f ? ax : LEAKY_SLOPE * ax;
    ay = ay > 0.f ? ay : LEAKY_SLOPE * ay;
    reinterpret_cast<float2*>(out)[(long long)wave * 64 + lane] =
        make_float2(ax, ay);
}

// ---------------- R0 fallback: atomic scatter ----------------

__global__ void gcn_scatter_kernel(const int* __restrict__ row_idx,
                                   const int* __restrict__ col_idx,
                                   const float* __restrict__ vals,
                                   const float* __restrict__ embeds,
                                   float* __restrict__ out,
                                   int E) {
    long long tid = (long long)blockIdx.x * blockDim.x + threadIdx.x;
    long long e = tid >> 5;
    if (e >= E) return;
    int q = (int)(tid & 31);
    int row = row_idx[e];
    int col = col_idx[e];
    float v = vals[e];
    const float4* src =
        reinterpret_cast<const float4*>(embeds + (long long)col * GCN_D) + q;
    float4 m = *src;
    float* dst = out + (long long)row * GCN_D + (long long)q * 4;
    atomicAdd(dst + 0, v * m.x);
    atomicAdd(dst + 1, v * m.y);
    atomicAdd(dst + 2, v * m.z);
    atomicAdd(dst + 3, v * m.w);
}

__global__ void gcn_leaky_relu_kernel(float* __restrict__ out, int n4) {
    int i = blockIdx.x * blockDim.x + threadIdx.x;
    if (i >= n4) return;
    float4* p = reinterpret_cast<float4*>(out) + i;
    float4 x = *p;
    x.x = x.x > 0.f ? x.x : LEAKY_SLOPE * x.x;
    x.y = x.y > 0.f ? x.y : LEAKY_SLOPE * x.y;
    x.z = x.z > 0.f ? x.z : LEAKY_SLOPE * x.z;
    x.w = x.w > 0.f ? x.w : LEAKY_SLOPE * x.w;
    *p = x;
}

// ---------------------------------------------------------------------------

extern "C" void kernel_launch(void* const* d_in, const int* in_sizes, int n_in,
                              void* d_out, int out_size, void* d_ws, size_t ws_size,
                              hipStream_t stream) {
    const int*   edge_index = (const int*)d_in[0];   // (2, E) flat, int32
    const float* edge_vals  = (const float*)d_in[1]; // (E,)
    const float* embeds     = (const float*)d_in[2]; // (N, 128) f32
    float*       out        = (float*)d_out;         // (N, 128) f32

    const int E = in_sizes[1];
    const int N = out_size / GCN_D;                  // 100000
    const int* row = edge_index;
    const int* col = edge_index + E;

    const int block = 256;

    // R5 ws layout: head[NCHAIN][N] | node[E] int4 | half-embeds[N*128] f16
    size_t head_b  = (size_t)NCHAIN * N * sizeof(int);       // 3.2 MB
    size_t node_b  = (size_t)E * sizeof(int4);               // 51.2 MB
    size_t half_b  = (size_t)N * GCN_D * sizeof(__half);     // 25.6 MB
    size_t need_r5 = head_b + node_b + half_b;
    size_t head_fb = (size_t)N * NCHAIN_FB * sizeof(int);
    size_t need_r3 = head_fb + node_b;

    if (ws_size >= need_r5) {
        int*   head = (int*)d_ws;
        i32x4* node = reinterpret_cast<i32x4*>((char*)d_ws + head_b);
        u32x4* h8   = reinterpret_cast<u32x4*>((char*)d_ws + head_b + node_b);

        hipMemsetAsync(head, 0xFF, head_b, stream);

        int n8 = N * (GCN_D / 8);                     // 1.6M groups of 8 floats
        int buildBlocks = 2048;
        int convBlocks  = (n8 + block - 1) / block;   // 6250
        build_convert_kernel<<<buildBlocks + convBlocks, block, 0, stream>>>(
            row, col, edge_vals, E, N,
            reinterpret_cast<const f32x4*>(embeds), n8, h8,
            head, node, buildBlocks);

        long long threads = (long long)N * 64;        // one wave per row
        int rblocks = (int)((threads + block - 1) / block);
        reduce_half8_kernel<<<rblocks, block, 0, stream>>>(
            head, node, reinterpret_cast<const __half2*>(h8), out, N);
    } else if (ws_size >= need_r3) {
        int*  head = (int*)d_ws;
        int4* node = reinterpret_cast<int4*>((char*)d_ws + head_fb);

        hipMemsetAsync(head, 0xFF, head_fb, stream);
        build_nodes_kernel<<<2048, block, 0, stream>>>(row, col, edge_vals,
                                                       E, head, node);

        long long threads = (long long)N * 64;
        int rblocks = (int)((threads + block - 1) / block);
        reduce_nodes_kernel<<<rblocks, block, 0, stream>>>(
            head, node, embeds, out, N);
    } else {
        hipMemsetAsync(d_out, 0, (size_t)out_size * sizeof(float), stream);
        long long total_threads = (long long)E * 32;
        long long grid = (total_threads + block - 1) / block;
        gcn_scatter_kernel<<<(unsigned)grid, block, 0, stream>>>(
            row, col, edge_vals, embeds, out, E);
        int n4 = out_size / 4;
        gcn_leaky_relu_kernel<<<(n4 + 255) / 256, 256, 0, stream>>>(out, n4);
    }
}